// Round 2
// baseline (786.401 us; speedup 1.0000x reference)
//
#include <hip/hip_runtime.h>

#define B_N    64
#define L_N    2048
#define D_N    960
#define DLAT_N 512
#define CH     256
#define NF4    (D_N / 4)    // 240

// workspace offsets (in floats) — fixed header, variable-size VP tail
#define O_BCT   0                        // BcT  (16 x 960)      = 15360
#define O_HCT   (O_BCT + 15360)          // HcT  (512 x 256)     = 131072
#define O_W1T   (O_HCT + 131072)         // W1T  (512 x 512)     = 262144
#define O_W2T   (O_W1T + 262144)         // W2T  (512 x 512)     = 262144
#define O_U     (O_W2T + 262144)         // U    (64 x 256)      = 16384
#define O_ZT    (O_U + 16384)            // zT   (512 x 64)      = 32768
#define O_HNT   (O_ZT + 32768)           // hnT  (512 x 64)      = 32768
#define O_FLAGS (O_HNT + 32768)          // up to 512 ints
#define O_VP    (O_FLAGS + 512)          // B_N*NCW x (16 x 960) partials

// ---------------------------------------------------------------------------
// K0: transpose the four small weight matrices into ws (total 2.7 MB, ~1 us).
__global__ __launch_bounds__(256) void k0_t(const float* __restrict__ Bc,
                                            const float* __restrict__ Hc,
                                            const float* __restrict__ W1,
                                            const float* __restrict__ W2,
                                            float* __restrict__ ws) {
    int idx = blockIdx.x * 256 + threadIdx.x;
    if (idx < 15360) {                     // Bc (960,16) -> BcT (16,960)
        int i = idx >> 4, j = idx & 15;
        ws[O_BCT + j * D_N + i] = Bc[idx];
        return;
    }
    idx -= 15360;
    if (idx < 131072) {                    // Hc (256,512) -> HcT (512,256)
        int i = idx >> 9, j = idx & 511;
        ws[O_HCT + j * 256 + i] = Hc[idx];
        return;
    }
    idx -= 131072;
    if (idx < 262144) {                    // W1 (512,512) -> W1T
        int i = idx >> 9, j = idx & 511;
        ws[O_W1T + j * 512 + i] = W1[idx];
        return;
    }
    idx -= 262144;
    {                                      // W2 (512,512) -> W2T
        int i = idx >> 9, j = idx & 511;
        ws[O_W2T + j * 512 + i] = W2[idx];
    }
}

// ---------------------------------------------------------------------------
// K1: V-partial[blk][p][d] = sum_{l in block's rows, mask!=0} (Ac[l][p]*mask)*emb[l][d]
// Grid = B_N * NCW blocks; each block owns L_N/NCW rows, processed in 256-row
// tiles. Thread t<240 owns d-columns 4t..4t+3 and all 16 p-accumulators in
// registers (no cross-lane reduction). Active rows ballot-compacted per tile
// -> branch-free streaming with depth-2 float4 prefetch; masked rows are
// skipped entirely (exact: their contribution is 0).
template <int NCW>
__global__ __launch_bounds__(256) void k1_v(const float* __restrict__ emb,
                                            const float* __restrict__ mask,
                                            const float* __restrict__ Ac,
                                            float* __restrict__ ws) {
    constexpr int RPB = L_N / NCW;       // rows per block
    constexpr int NT  = RPB / CH;        // 256-row tiles per block
    const int blk = blockIdx.x;
    const int b = blk / NCW, c = blk % NCW;
    const int t = threadIdx.x;
    const int lane = t & 63, wv = t >> 6;

    __shared__ __align__(16) float w_lds[CH][16];
    __shared__ float m_lds[CH];
    __shared__ short act[CH];
    __shared__ int   cnt[4];

    float acc[16][4];
#pragma unroll
    for (int p = 0; p < 16; ++p) {
        acc[p][0] = 0.f; acc[p][1] = 0.f; acc[p][2] = 0.f; acc[p][3] = 0.f;
    }

    int any = 0;
    const int row0 = c * RPB;

    for (int tile = 0; tile < NT; ++tile) {
        const int rbase = row0 + tile * CH;

        float mv = mask[b * L_N + rbase + t];
        m_lds[t] = mv;
        unsigned long long bal = __ballot(mv != 0.f);
        if (lane == 0) cnt[wv] = (int)__popcll(bal);
        __syncthreads();

        const int total = cnt[0] + cnt[1] + cnt[2] + cnt[3];   // block-uniform
        if (total > 0) {
            any = 1;
            int base = 0;
            for (int i = 0; i < wv; ++i) base += cnt[i];
            if (mv != 0.f) {
                int rank = (int)__popcll(bal & ((1ull << lane) - 1ull));
                act[base + rank] = (short)t;
            }
            // w_lds[l][p] = Ac[rbase+l][p] * mask[rbase+l]
            const float4* Ac4 = (const float4*)(Ac + (size_t)rbase * 16);
            float4* w4 = (float4*)&w_lds[0][0];
            for (int i = t; i < CH * 4; i += 256) {
                float4 a = Ac4[i];
                float m = m_lds[i >> 2];
                a.x *= m; a.y *= m; a.z *= m; a.w *= m;
                w4[i] = a;
            }
            __syncthreads();

            if (t < NF4) {
                const float4* row4 =
                    (const float4*)(emb + (size_t)b * L_N * D_N + (size_t)rbase * D_N);
                int r0 = act[0];
                int r1 = (total > 1) ? act[1] : r0;
                float4 v0 = row4[r0 * NF4 + t];
                float4 v1 = row4[r1 * NF4 + t];

                for (int i = 0; i < total; ++i) {
                    float4 v = v0;
                    int l = r0;
                    r0 = r1; v0 = v1;
                    if (i + 2 < total) { r1 = act[i + 2]; v1 = row4[r1 * NF4 + t]; }

                    float4 wA = *(const float4*)&w_lds[l][0];
                    float4 wB = *(const float4*)&w_lds[l][4];
                    float4 wC = *(const float4*)&w_lds[l][8];
                    float4 wD = *(const float4*)&w_lds[l][12];
#define ACC4(P, WW) acc[P][0] += (WW) * v.x; acc[P][1] += (WW) * v.y; \
                    acc[P][2] += (WW) * v.z; acc[P][3] += (WW) * v.w;
                    ACC4(0, wA.x)  ACC4(1, wA.y)  ACC4(2, wA.z)  ACC4(3, wA.w)
                    ACC4(4, wB.x)  ACC4(5, wB.y)  ACC4(6, wB.z)  ACC4(7, wB.w)
                    ACC4(8, wC.x)  ACC4(9, wC.y)  ACC4(10, wC.z) ACC4(11, wC.w)
                    ACC4(12, wD.x) ACC4(13, wD.y) ACC4(14, wD.z) ACC4(15, wD.w)
#undef ACC4
                }
            }
        }
        __syncthreads();   // protect LDS reuse across tiles
    }

    int* flags = (int*)(ws + O_FLAGS);
    if (t == 0) flags[blk] = any;
    if (!any || t >= NF4) return;

    float* vp = ws + O_VP + (size_t)blk * (16 * D_N);
#pragma unroll
    for (int p = 0; p < 16; ++p) {
        float4 o; o.x = acc[p][0]; o.y = acc[p][1]; o.z = acc[p][2]; o.w = acc[p][3];
        ((float4*)(vp + p * D_N))[t] = o;
    }
}

// ---------------------------------------------------------------------------
// K2: reduce active partials -> V[b] slice, then U[b,p,r] += V@Bc over the
// block's 240-column d-slice. Grid (64 b x 4 d-slices), atomicAdd into U.
template <int NCW>
__global__ __launch_bounds__(256) void k2_u(float* __restrict__ ws) {
    const int b = blockIdx.x >> 2, ds = blockIdx.x & 3;
    const int t = threadIdx.x;
    __shared__ __align__(16) float V[16 * 240];

    const int* flags = (const int*)(ws + O_FLAGS);
    int f[NCW];
#pragma unroll
    for (int c = 0; c < NCW; ++c) f[c] = flags[b * NCW + c];

    for (int idx = t; idx < 16 * 60; idx += 256) {
        int p = idx / 60, q = idx - p * 60;
        float4 a; a.x = 0.f; a.y = 0.f; a.z = 0.f; a.w = 0.f;
#pragma unroll
        for (int c = 0; c < NCW; ++c) {
            if (f[c]) {
                const float4* vp4 = (const float4*)(ws + O_VP +
                    (size_t)(b * NCW + c) * (16 * D_N) + p * D_N + ds * 240);
                float4 x = vp4[q];
                a.x += x.x; a.y += x.y; a.z += x.z; a.w += x.w;
            }
        }
        ((float4*)V)[idx] = a;
    }
    __syncthreads();

    const int p = t >> 4, r = t & 15;
    const float4* bt4 = (const float4*)(ws + O_BCT + r * D_N + ds * 240);
    const float4* v4  = (const float4*)(V + p * 240);
    float u = 0.f;
#pragma unroll 4
    for (int q = 0; q < 60; ++q) {
        float4 vv = v4[q], bb = bt4[q];
        u += vv.x * bb.x + vv.y * bb.y + vv.z * bb.z + vv.w * bb.w;
    }
    atomicAdd(ws + O_U + b * 256 + p * 16 + r, u);
}

// ---------------------------------------------------------------------------
// K3: z[b][j] = sum_k U[b][k] * Hc[k][j]; write transposed zT[j][b].
__global__ __launch_bounds__(256) void k3_z(float* __restrict__ ws) {
    const int b = blockIdx.x, t = threadIdx.x;
    __shared__ float4 U4[64];
    if (t < 64) U4[t] = ((const float4*)(ws + O_U + b * 256))[t];
    __syncthreads();
    for (int j = t; j < DLAT_N; j += 256) {
        const float4* h4 = (const float4*)(ws + O_HCT + (size_t)j * 256);
        float acc = 0.f;
#pragma unroll 8
        for (int k = 0; k < 64; ++k) {
            float4 u = U4[k], hh = h4[k];
            acc += u.x * hh.x + u.y * hh.y + u.z * hh.z + u.w * hh.w;
        }
        ws[O_ZT + (size_t)j * B_N + b] = acc;
    }
}

// ---------------------------------------------------------------------------
// K4: h = z@W1 + b1, BatchNorm over the 64-sample batch (one feature per
// block, one sample per lane; 64-lane shuffle reduce for mean/var), ReLU.
__global__ __launch_bounds__(64) void k4_bn(const float* __restrict__ b1,
                                            const float* __restrict__ gamma,
                                            const float* __restrict__ beta,
                                            float* __restrict__ ws) {
    const int j = blockIdx.x, b = threadIdx.x;
    const float* zT = ws + O_ZT;
    const float* w1 = ws + O_W1T + (size_t)j * DLAT_N;
    float h = b1[j];
#pragma unroll 8
    for (int i = 0; i < DLAT_N; ++i) h += zT[i * B_N + b] * w1[i];

    float s = h, s2 = h * h;
#pragma unroll
    for (int off = 32; off > 0; off >>= 1) {
        s  += __shfl_xor(s, off);
        s2 += __shfl_xor(s2, off);
    }
    float mean = s * (1.f / B_N);
    float var  = s2 * (1.f / B_N) - mean * mean;   // biased, as torch BN
    float sc = gamma[j] * rsqrtf(var + 1e-5f);
    float hn = fmaxf((h - mean) * sc + beta[j], 0.f);
    ws[O_HNT + (size_t)j * B_N + b] = hn;
}

// ---------------------------------------------------------------------------
// K5: out[b][j] = sum_i hn[b][i] * W2[i][j] + b2[j]
__global__ __launch_bounds__(64) void k5_out(const float* __restrict__ b2,
                                             const float* __restrict__ ws,
                                             float* __restrict__ out) {
    const int j = blockIdx.x, b = threadIdx.x;
    const float* hnT = ws + O_HNT;
    const float* w2 = ws + O_W2T + (size_t)j * DLAT_N;
    float acc = 0.f;
#pragma unroll 8
    for (int i = 0; i < DLAT_N; ++i) acc += hnT[i * B_N + b] * w2[i];
    out[(size_t)b * DLAT_N + j] = acc + b2[j];
}

// ---------------------------------------------------------------------------
extern "C" void kernel_launch(void* const* d_in, const int* in_sizes, int n_in,
                              void* d_out, int out_size, void* d_ws, size_t ws_size,
                              hipStream_t stream) {
    const float* emb   = (const float*)d_in[0];
    const float* mask  = (const float*)d_in[1];
    const float* Bc    = (const float*)d_in[2];
    const float* Ac    = (const float*)d_in[3];
    const float* Hc    = (const float*)d_in[4];
    const float* W1    = (const float*)d_in[5];
    const float* b1    = (const float*)d_in[6];
    const float* gamma = (const float*)d_in[7];
    const float* beta  = (const float*)d_in[8];
    const float* W2    = (const float*)d_in[9];
    const float* b2    = (const float*)d_in[10];
    float* ws  = (float*)d_ws;
    float* out = (float*)d_out;

    // pick the largest chunk count whose V-partials fit in ws
    auto need = [](int n) {
        return (size_t)(O_VP + (size_t)B_N * n * 16 * D_N) * sizeof(float);
    };
    int ncw = 1;
    if      (ws_size >= need(8)) ncw = 8;
    else if (ws_size >= need(4)) ncw = 4;
    else if (ws_size >= need(2)) ncw = 2;

    hipLaunchKernelGGL(k0_t, dim3(2620), dim3(256), 0, stream, Bc, Hc, W1, W2, ws);
    switch (ncw) {
    case 8: hipLaunchKernelGGL((k1_v<8>), dim3(B_N * 8), dim3(256), 0, stream, emb, mask, Ac, ws); break;
    case 4: hipLaunchKernelGGL((k1_v<4>), dim3(B_N * 4), dim3(256), 0, stream, emb, mask, Ac, ws); break;
    case 2: hipLaunchKernelGGL((k1_v<2>), dim3(B_N * 2), dim3(256), 0, stream, emb, mask, Ac, ws); break;
    default: hipLaunchKernelGGL((k1_v<1>), dim3(B_N), dim3(256), 0, stream, emb, mask, Ac, ws); break;
    }
    hipMemsetAsync(ws + O_U, 0, 16384 * sizeof(float), stream);
    switch (ncw) {
    case 8: hipLaunchKernelGGL((k2_u<8>), dim3(B_N * 4), dim3(256), 0, stream, ws); break;
    case 4: hipLaunchKernelGGL((k2_u<4>), dim3(B_N * 4), dim3(256), 0, stream, ws); break;
    case 2: hipLaunchKernelGGL((k2_u<2>), dim3(B_N * 4), dim3(256), 0, stream, ws); break;
    default: hipLaunchKernelGGL((k2_u<1>), dim3(B_N * 4), dim3(256), 0, stream, ws); break;
    }
    hipLaunchKernelGGL(k3_z, dim3(B_N), dim3(256), 0, stream, ws);
    hipLaunchKernelGGL(k4_bn, dim3(DLAT_N), dim3(64), 0, stream, b1, gamma, beta, ws);
    hipLaunchKernelGGL(k5_out, dim3(DLAT_N), dim3(64), 0, stream, b2, ws, out);
}